// Round 8
// baseline (164.124 us; speedup 1.0000x reference)
//
#include <hip/hip_runtime.h>
#include <math.h>

// ChamferLoss: pred [32,4096,3] f32, gt [32,4096,3] f32 -> scalar f32.
//
// R12. R11 (93us) post-mortem: VALUBusy 28% (26us busy = inst count), 72%
// idle at occupancy 71% -> barrier-drain bound: each chunk had only ~300cy
// compute between two __syncthreads that drain a ~500-900cy global staging
// load; all blocks stall in lockstep, so occupancy can't help. R10 was
// faster only because its chunks carried 2x compute. R12 removes the
// barriers from the hot loop entirely:
//  - NO LDS staging for B: each wave streams its own Bfrag tiles with
//    coalesced 1KB/wave loads, register-prefetched 2 tiles ahead
//    (rolling cur/nxt/fut, unconditional; 2-tile overread stays inside ws).
//  - 2 A-frags per wave (64 gt rows) -> 2 MFMA + ~64 VALU (~150cy) per
//    16B load: latency-tolerant at depth 2.
//  - Waves split cols 8-way; each wave OWNS its 512 sPmin cols -> plain
//    write-once LDS float stores (no atomics, no init, no conflicts).
//  - Only 2 barriers per block total (before the two epilogues).
// Numerics identical to R11 (absmax 0.0): d2 fully inside
// mfma_f32_32x32x16_bf16, 2-way split, K=16 exact.
//
// Layouts (m74/m101-verified, 32x32x16 bf16):
//   A: row = lane&31, k = 8*(lane>>5)+i
//   B: col = lane&31, k = 8*(lane>>5)+i
//   C: col = lane&31, row = (reg&3) + 8*(reg>>2) + 4*(lane>>5)
// K-slot map (A = -2*gt split h/m, B = pred split h/m):
//   k0-5: Ah*(Bh,Bm)  k6-11: Am*(Bh,Bm)  k12-13: G2h,G2m*1  k14-15: 1*P2h,P2m

typedef short short8 __attribute__((ext_vector_type(8)));
typedef float f32x16 __attribute__((ext_vector_type(16)));
typedef unsigned int uint;

#define NPTS  4096
#define TPBM  512           // 8 waves, all col-split (512 cols each)
#define TPBP  256
#define NPANEL 64           // 64-row gt panels per batch
#define GRID_MAIN (32 * NPANEL)              // 2048
#define NBT   128           // B-tiles per batch (32 cols each)
#define ONEB ((short)0x3F80)                 // bf16 1.0

// ---- bf16 split helpers (RNE) ----
__device__ __forceinline__ unsigned short bf16h(float f) {
    uint u = __float_as_uint(f);
    uint r = u + 0x7FFFu + ((u >> 16) & 1u);
    return (unsigned short)(r >> 16);
}
__device__ __forceinline__ float bf16f(unsigned short h) {
    return __uint_as_float(((uint)h) << 16);
}
struct Split2 { unsigned short h, m; };
__device__ __forceinline__ Split2 split2(float x) {
    Split2 s;
    s.h = bf16h(x);
    s.m = bf16h(x - bf16f(s.h));
    return s;
}

// ---- prep: pred -> B-fragments + wspred init (one thread per frag-lane) ----
__global__ __launch_bounds__(TPBP) void chamfer_prep(
    const float* __restrict__ pred, short8* __restrict__ Bfrag,
    uint* __restrict__ wspred)
{
    const int gid = blockIdx.x * TPBP + threadIdx.x;   // 262144 total
    if (gid < 32 * NPTS) wspred[gid] = 0xFFFFFFFFu;    // atomicMin identity

    const int lane = gid & 63;
    const int ent  = gid >> 6;          // b*128 + tile
    const int b    = ent >> 7;
    const int tile = ent & 127;
    const int c31  = lane & 31, half = lane >> 5;

    const float* p = pred + ((size_t)(b * NPTS + tile * 32 + c31)) * 3;
    float x = p[0], y = p[1], z = p[2];
    Split2 X = split2(x), Y = split2(y), Z = split2(z);
    Split2 P2 = split2(fmaf(x, x, fmaf(y, y, z * z)));

    short8 f;
    if (half == 0) {
        f[0]=(short)X.h; f[1]=(short)Y.h; f[2]=(short)Z.h;
        f[3]=(short)X.m; f[4]=(short)Y.m; f[5]=(short)Z.m;
        f[6]=(short)X.h; f[7]=(short)Y.h;
    } else {
        f[0]=(short)Z.h; f[1]=(short)X.m; f[2]=(short)Y.m; f[3]=(short)Z.m;
        f[4]=ONEB;       f[5]=ONEB;       f[6]=(short)P2.h; f[7]=(short)P2.m;
    }
    Bfrag[gid] = f;
}

// ---- main: per block = (batch, 64 gt rows) x all 4096 pred cols ----
__global__ __launch_bounds__(TPBM, 4) void chamfer_mfma(
    const float* __restrict__ gt,
    uint* __restrict__ wspred,
    float* __restrict__ wsgt,
    const short8* __restrict__ Bfrag)
{
    const int bx    = blockIdx.x;      // 2048 = b(32) x panel(64)
    const int b     = bx >> 6;
    const int panel = bx & 63;
    const int tid   = threadIdx.x;
    const int lane  = tid & 63, wid = tid >> 6;    // wid = col-eighth
    const int c31   = lane & 31, half = lane >> 5;

    __shared__ float sPmin[NPTS];    // 16 KB, write-once per slot
    __shared__ float sred[64 * 8];   // 2 KB: gt-side [row_local][wid]

    // 2 A-frags: rows panel*64 + fr*32 + c31, coords scaled -2, g2 baked in.
    const float* gtb = gt + (size_t)b * NPTS * 3;
    short8 afr[2];
    float gm[2][16];
#pragma unroll
    for (int fr = 0; fr < 2; ++fr) {
        const int row = panel * 64 + fr * 32 + c31;
        const float* ap = gtb + (size_t)row * 3;
        float x = ap[0], y = ap[1], z = ap[2];
        Split2 X = split2(-2.0f*x), Y = split2(-2.0f*y), Z = split2(-2.0f*z);
        Split2 G2 = split2(fmaf(x, x, fmaf(y, y, z * z)));
        short8 a;
        if (half == 0) {
            a[0]=(short)X.h; a[1]=(short)Y.h; a[2]=(short)Z.h;
            a[3]=(short)X.h; a[4]=(short)Y.h; a[5]=(short)Z.h;
            a[6]=(short)X.m; a[7]=(short)Y.m;
        } else {
            a[0]=(short)Z.m; a[1]=(short)X.m; a[2]=(short)Y.m; a[3]=(short)Z.m;
            a[4]=(short)G2.h; a[5]=(short)G2.m; a[6]=ONEB; a[7]=ONEB;
        }
        afr[fr] = a;
#pragma unroll
        for (int r = 0; r < 16; ++r) gm[fr][r] = 1e30f;
    }

    // B stream: this wave's 16 tiles, prefetched 2 ahead (rolling regs).
    // Unconditional fut loads overread <=2 tiles (32KB max past Bfrag of the
    // last batch) -- lands in unused ws, values never consumed.
    const size_t bfb = (size_t)b * (NBT * 64);
    const short8* bp = Bfrag + bfb + ((size_t)(wid * 16) << 6) + lane;
    const f32x16 zero = {0.f,0.f,0.f,0.f,0.f,0.f,0.f,0.f,
                         0.f,0.f,0.f,0.f,0.f,0.f,0.f,0.f};

    short8 cur = bp[0];
    short8 nxt = bp[64];
#pragma unroll 4
    for (int t = 0; t < 16; ++t) {
        short8 fut = bp[(size_t)(t + 2) * 64];   // prefetch depth 2
        f32x16 a0 = __builtin_amdgcn_mfma_f32_32x32x16_bf16(
            afr[0], cur, zero, 0, 0, 0);
        f32x16 a1 = __builtin_amdgcn_mfma_f32_32x32x16_bf16(
            afr[1], cur, zero, 0, 0, 0);

        float pmin = 1e30f;
#pragma unroll
        for (int r = 0; r < 16; ++r) {
            gm[0][r] = fminf(gm[0][r], a0[r]);           // gt row-mins
            gm[1][r] = fminf(gm[1][r], a1[r]);
            pmin = fminf(pmin, fminf(a0[r], a1[r]));     // v_min3 fold
        }
        // fold the two halves (complementary rows, same col) -> 64-row min
        pmin = fminf(pmin, __shfl_xor(pmin, 32, 64));
        // wave owns these cols: plain write-once store (both halves same val)
        sPmin[wid * 512 + t * 32 + c31] = fmaxf(pmin, 1e-12f);

        cur = nxt; nxt = fut;
    }
    __syncthreads();   // sPmin complete

    // pred-side epilogue: batched guarded atomicMin, coalesced
    uint* wsb = wspred + (size_t)b * NPTS;
    for (int c = tid; c < NPTS; c += TPBM) {
        const uint mine = __float_as_uint(sPmin[c]);   // >0: uint order==float
        if (mine < wsb[c]) atomicMin(&wsb[c], mine);
    }

    // gt-side: fold row-mins across the 32 cols (c31 lanes, per half)
#pragma unroll
    for (int off = 1; off < 32; off <<= 1)
#pragma unroll
        for (int fr = 0; fr < 2; ++fr)
#pragma unroll
            for (int r = 0; r < 16; ++r)
                gm[fr][r] = fminf(gm[fr][r], __shfl_xor(gm[fr][r], off, 64));
    if (c31 == 0) {
#pragma unroll
        for (int fr = 0; fr < 2; ++fr)
#pragma unroll
            for (int r = 0; r < 16; ++r)
                sred[(fr*32 + (r&3) + 8*(r>>2) + 4*half) * 8 + wid] = gm[fr][r];
    }
    __syncthreads();

    if (tid < 64) {   // wave 0: fold 8 wid-partials, sqrt, sum -> wsgt[bx]
        float v = 1e30f;
#pragma unroll
        for (int w = 0; w < 8; ++w) v = fminf(v, sred[tid * 8 + w]);
        float s = sqrtf(fmaxf(v, 1e-12f));
#pragma unroll
        for (int off = 32; off > 0; off >>= 1) s += __shfl_down(s, off, 64);
        if (tid == 0) wsgt[bx] = s;
    }
}

// ---- finish: sum sqrt(pred mins) + gt partials -> out ----
__global__ __launch_bounds__(TPBP) void chamfer_finish(
    const uint* __restrict__ wspred, const float* __restrict__ wsgt,
    float* __restrict__ out)
{
    __shared__ float swv[TPBP / 64];
    const int tid  = threadIdx.x;
    const int base = blockIdx.x * (TPBP * 4) + tid;   // 128 blocks x 1024

    float s = 0.0f;
#pragma unroll
    for (int r = 0; r < 4; ++r)
        s += sqrtf(__uint_as_float(wspred[base + r * TPBP]));
    if (blockIdx.x == 0) {
#pragma unroll
        for (int r = 0; r < 8; ++r)
            s += wsgt[tid + r * TPBP];   // 2048 per-block gt partials
    }

#pragma unroll
    for (int off = 32; off > 0; off >>= 1) s += __shfl_down(s, off, 64);
    const int wid = tid >> 6, lane = tid & 63;
    if (lane == 0) swv[wid] = s;
    __syncthreads();
    if (tid == 0) {
        float tot = swv[0] + swv[1] + swv[2] + swv[3];
        atomicAdd(out, tot * (1.0f / 131072.0f));
    }
}

extern "C" void kernel_launch(void* const* d_in, const int* in_sizes, int n_in,
                              void* d_out, int out_size, void* d_ws, size_t ws_size,
                              hipStream_t stream)
{
    const float* pred = (const float*)d_in[0];
    const float* gt   = (const float*)d_in[1];
    float* out        = (float*)d_out;

    // ws layout: [0,512K) wspred uints; [512K,+8K) wsgt; [1M,5M) Bfrag
    // (+<=32KB overread slack after Bfrag stays inside ws)
    uint*   wspred = (uint*)d_ws;
    float*  wsgt   = (float*)((char*)d_ws + (512 << 10));
    short8* Bfrag  = (short8*)((char*)d_ws + (1 << 20));

    hipMemsetAsync(d_out, 0, sizeof(float), stream);

    chamfer_prep<<<dim3((32 * NBT * 64) / TPBP), dim3(TPBP), 0, stream>>>(
        pred, Bfrag, wspred);
    chamfer_mfma<<<dim3(GRID_MAIN), dim3(TPBM), 0, stream>>>(
        gt, wspred, wsgt, Bfrag);
    chamfer_finish<<<dim3(128), dim3(TPBP), 0, stream>>>(wspred, wsgt, out);
}

// Round 9
// 101.789 us; speedup vs baseline: 1.6124x; 1.6124x over previous
//
#include <hip/hip_runtime.h>
#include <math.h>

// ChamferLoss: pred [32,4096,3] f32, gt [32,4096,3] f32 -> scalar f32.
//
// R13. Synthesis of R10-R12 evidence:
//  - R10 (70us, best): LDS-staged B, 2 barriers/chunk, ~40% idle from the
//    vmcnt(0) barrier drain; ~8 MFMA-equiv per staged KB.
//  - R11 (93us): same structure, HALF the compute per chunk -> drain-bound.
//  - R12 (111us): barrier-free streaming, but compiler's occupancy heuristic
//    allocated 64 VGPR for ~100 live -> AGPR shuffling (VALUBusy 42.8% with
//    3x inflated busy time), and MFMA->fold consumed with no slack.
// R13 = R10's structure + double compute density + async-stage + reg cap:
//  - Block = 256 gt rows x 4096 cols, 8 waves = rw(4) x cq(2), 2 A-frags
//    per wave. Per 32KB chunk: 16 t-iters x (2 MFMA + ~50 VALU) ~ 2400cy
//    compute vs ~900cy stage -> 2.6x the R10 density. Grid 512 = 2
//    blocks/CU co-resident (LDS 50KB), drains overlap.
//  - T14 async-STAGE: chunk ch+1's global loads issue into registers right
//    after ds_write(ch); by next ds_write vmcnt is retired -> barrier
//    drains lgkm only.
//  - 32x32x16 K=16 2-way split (absmax 0.0 in R11+R12), half of R10's
//    staging bytes.
//  - __launch_bounds__(512,4): VGPR cap 128 >= ~105 live -> no AGPR dance.
//  - Pred-side merge: LDS atomicMin (2-way same-address per wave + 4 rw
//    waves), R10-proven; batched guarded global atomicMin epilogue.
//
// Layouts (m74/m101-verified, 32x32x16 bf16):
//   A: row = lane&31, k = 8*(lane>>5)+i
//   B: col = lane&31, k = 8*(lane>>5)+i
//   C: col = lane&31, row = (reg&3) + 8*(reg>>2) + 4*(lane>>5)
// K-slot map (A = -2*gt split h/m, B = pred split h/m):
//   k0-5: Ah*(Bh,Bm)  k6-11: Am*(Bh,Bm)  k12-13: G2h,G2m*1  k14-15: 1*P2h,P2m

typedef short short8 __attribute__((ext_vector_type(8)));
typedef float f32x16 __attribute__((ext_vector_type(16)));
typedef unsigned int uint;

#define NPTS  4096
#define TPBM  512           // 8 waves = rw(4) x cq(2)
#define TPBP  256
#define NPANEL 16           // 256-row gt panels per batch
#define GRID_MAIN (32 * NPANEL)              // 512
#define NBT   128           // B-tiles per batch (32 cols each)
#define CHT   16            // tiles per cq per chunk (chunk = 32KB)
#define NCH   4             // 64 tiles/cq / CHT
#define ONEB ((short)0x3F80)                 // bf16 1.0

// ---- bf16 split helpers (RNE) ----
__device__ __forceinline__ unsigned short bf16h(float f) {
    uint u = __float_as_uint(f);
    uint r = u + 0x7FFFu + ((u >> 16) & 1u);
    return (unsigned short)(r >> 16);
}
__device__ __forceinline__ float bf16f(unsigned short h) {
    return __uint_as_float(((uint)h) << 16);
}
struct Split2 { unsigned short h, m; };
__device__ __forceinline__ Split2 split2(float x) {
    Split2 s;
    s.h = bf16h(x);
    s.m = bf16h(x - bf16f(s.h));
    return s;
}

// ---- prep: pred -> B-fragments + wspred init (one thread per frag-lane) ----
__global__ __launch_bounds__(TPBP) void chamfer_prep(
    const float* __restrict__ pred, short8* __restrict__ Bfrag,
    uint* __restrict__ wspred)
{
    const int gid = blockIdx.x * TPBP + threadIdx.x;   // 262144 total
    if (gid < 32 * NPTS) wspred[gid] = 0xFFFFFFFFu;    // atomicMin identity

    const int lane = gid & 63;
    const int ent  = gid >> 6;          // b*128 + tile
    const int b    = ent >> 7;
    const int tile = ent & 127;
    const int c31  = lane & 31, half = lane >> 5;

    const float* p = pred + ((size_t)(b * NPTS + tile * 32 + c31)) * 3;
    float x = p[0], y = p[1], z = p[2];
    Split2 X = split2(x), Y = split2(y), Z = split2(z);
    Split2 P2 = split2(fmaf(x, x, fmaf(y, y, z * z)));

    short8 f;
    if (half == 0) {
        f[0]=(short)X.h; f[1]=(short)Y.h; f[2]=(short)Z.h;
        f[3]=(short)X.m; f[4]=(short)Y.m; f[5]=(short)Z.m;
        f[6]=(short)X.h; f[7]=(short)Y.h;
    } else {
        f[0]=(short)Z.h; f[1]=(short)X.m; f[2]=(short)Y.m; f[3]=(short)Z.m;
        f[4]=ONEB;       f[5]=ONEB;       f[6]=(short)P2.h; f[7]=(short)P2.m;
    }
    Bfrag[gid] = f;
}

// ---- main: per block = (batch, 256 gt rows) x all 4096 pred cols ----
__global__ __launch_bounds__(TPBM, 4) void chamfer_mfma(
    const float* __restrict__ gt,
    uint* __restrict__ wspred,
    float* __restrict__ wsgt,
    const short8* __restrict__ Bfrag)
{
    const int bx    = blockIdx.x;      // 512 = b(32) x panel(16)
    const int b     = bx >> 4;
    const int panel = bx & 15;
    const int tid   = threadIdx.x;
    const int lane  = tid & 63, wid = tid >> 6;
    const int rw    = wid >> 1;        // 0..3: 64-row group
    const int cq    = wid & 1;         // 0..1: 2048-col half
    const int c31   = lane & 31, half = lane >> 5;

    __shared__ short8 sB[2 * CHT * 64];   // 32 KB: [cq][t][lane]
    __shared__ uint   sPmin[NPTS];        // 16 KB: col-mins, uint-ordered
    __shared__ float  sred[256 * 2];      // 2 KB: gt-side [row_local][cq]
    __shared__ float  sw[8];

    for (int c = tid; c < NPTS; c += TPBM) sPmin[c] = 0x7F7FFFFFu;

    // 2 A-frags: rows panel*256 + rw*64 + fr*32 + c31; coords * -2, g2 baked.
    const float* gtb = gt + (size_t)b * NPTS * 3;
    short8 afr[2];
    float gm[2][16];
#pragma unroll
    for (int fr = 0; fr < 2; ++fr) {
        const int row = panel * 256 + rw * 64 + fr * 32 + c31;
        const float* ap = gtb + (size_t)row * 3;
        float x = ap[0], y = ap[1], z = ap[2];
        Split2 X = split2(-2.0f*x), Y = split2(-2.0f*y), Z = split2(-2.0f*z);
        Split2 G2 = split2(fmaf(x, x, fmaf(y, y, z * z)));
        short8 a;
        if (half == 0) {
            a[0]=(short)X.h; a[1]=(short)Y.h; a[2]=(short)Z.h;
            a[3]=(short)X.h; a[4]=(short)Y.h; a[5]=(short)Z.h;
            a[6]=(short)X.m; a[7]=(short)Y.m;
        } else {
            a[0]=(short)Z.m; a[1]=(short)X.m; a[2]=(short)Y.m; a[3]=(short)Z.m;
            a[4]=(short)G2.h; a[5]=(short)G2.m; a[6]=ONEB; a[7]=ONEB;
        }
        afr[fr] = a;
#pragma unroll
        for (int r = 0; r < 16; ++r) gm[fr][r] = 1e30f;
    }

    const size_t bfb = (size_t)b * (NBT * 64);
    const f32x16 zero = {0.f,0.f,0.f,0.f,0.f,0.f,0.f,0.f,
                         0.f,0.f,0.f,0.f,0.f,0.f,0.f,0.f};

    // T14 async-stage: pf regs hold the NEXT chunk's 32KB (4 x 16B/thread).
    short8 pf[4];
#pragma unroll
    for (int ps = 0; ps < 4; ++ps) {
        const int u = ps * TPBM + tid;
        const int ucq = u >> 10, ut = (u >> 6) & 15, ul = u & 63;
        pf[ps] = Bfrag[bfb + (size_t)((ucq * 64 + ut) * 64 + ul)];
    }

    for (int ch = 0; ch < NCH; ++ch) {
        __syncthreads();   // sB free (prev reads done); ch=0: init visible
#pragma unroll
        for (int ps = 0; ps < 4; ++ps) sB[ps * TPBM + tid] = pf[ps];
        __syncthreads();   // sB ready (drains lgkm; vmcnt long retired)

        const int chn = (ch + 1 < NCH) ? ch + 1 : ch;   // clamp (no overread)
#pragma unroll
        for (int ps = 0; ps < 4; ++ps) {
            const int u = ps * TPBM + tid;
            const int ucq = u >> 10, ut = (u >> 6) & 15, ul = u & 63;
            pf[ps] = Bfrag[bfb + (size_t)((ucq * 64 + chn * CHT + ut) * 64 + ul)];
        }

#pragma unroll 2
        for (int t = 0; t < CHT; ++t) {
            short8 bfr = sB[(cq * CHT + t) * 64 + lane];
            f32x16 a0 = __builtin_amdgcn_mfma_f32_32x32x16_bf16(
                afr[0], bfr, zero, 0, 0, 0);
            f32x16 a1 = __builtin_amdgcn_mfma_f32_32x32x16_bf16(
                afr[1], bfr, zero, 0, 0, 0);

            float pmin = 1e30f;
#pragma unroll
            for (int r = 0; r < 16; ++r) {
                gm[0][r] = fminf(gm[0][r], a0[r]);            // gt row-mins
                gm[1][r] = fminf(gm[1][r], a1[r]);
                pmin = fminf(fminf(a0[r], a1[r]), pmin);      // v_min3
            }
            // this lane's 32-row col-min -> LDS atomic folds halves + rw waves
            atomicMin(&sPmin[cq * 2048 + (ch * CHT + t) * 32 + c31],
                      __float_as_uint(fmaxf(pmin, 1e-12f)));
        }
    }
    __syncthreads();   // sPmin complete

    // pred-side epilogue: batched guarded atomicMin, coalesced (16 panels/b)
    uint* wsb = wspred + (size_t)b * NPTS;
    for (int c = tid; c < NPTS; c += TPBM) {
        const uint mine = sPmin[c];
        if (mine < wsb[c]) atomicMin(&wsb[c], mine);
    }

    // gt-side: fold row-mins across the 32 cols (c31 lanes, within half)
#pragma unroll
    for (int off = 1; off < 32; off <<= 1)
#pragma unroll
        for (int fr = 0; fr < 2; ++fr)
#pragma unroll
            for (int r = 0; r < 16; ++r)
                gm[fr][r] = fminf(gm[fr][r], __shfl_xor(gm[fr][r], off, 64));
    if (c31 == 0) {   // lanes 0 and 32 (half 0/1) hold disjoint rows
#pragma unroll
        for (int fr = 0; fr < 2; ++fr)
#pragma unroll
            for (int r = 0; r < 16; ++r)
                sred[(rw*64 + fr*32 + (r&3) + 8*(r>>2) + 4*half) * 2 + cq]
                    = gm[fr][r];
    }
    __syncthreads();

    float ssum = 0.0f;
    if (tid < 256) {   // 256 rows: fold 2 cq, sqrt
        float v = fminf(sred[tid * 2], sred[tid * 2 + 1]);
        ssum = sqrtf(fmaxf(v, 1e-12f));
    }
#pragma unroll
    for (int off = 32; off > 0; off >>= 1) ssum += __shfl_down(ssum, off, 64);
    if (lane == 0) sw[wid] = ssum;
    __syncthreads();
    if (tid == 0)
        wsgt[bx] = sw[0]+sw[1]+sw[2]+sw[3]+sw[4]+sw[5]+sw[6]+sw[7];
}

// ---- finish: sum sqrt(pred mins) + gt partials -> out ----
__global__ __launch_bounds__(TPBP) void chamfer_finish(
    const uint* __restrict__ wspred, const float* __restrict__ wsgt,
    float* __restrict__ out)
{
    __shared__ float swv[TPBP / 64];
    const int tid  = threadIdx.x;
    const int base = blockIdx.x * (TPBP * 4) + tid;   // 128 blocks x 1024

    float s = 0.0f;
#pragma unroll
    for (int r = 0; r < 4; ++r)
        s += sqrtf(__uint_as_float(wspred[base + r * TPBP]));
    if (blockIdx.x == 0) {
#pragma unroll
        for (int r = 0; r < 2; ++r)
            s += wsgt[tid + r * TPBP];   // 512 per-block gt partials
    }

#pragma unroll
    for (int off = 32; off > 0; off >>= 1) s += __shfl_down(s, off, 64);
    const int wid = tid >> 6, lane = tid & 63;
    if (lane == 0) swv[wid] = s;
    __syncthreads();
    if (tid == 0) {
        float tot = swv[0] + swv[1] + swv[2] + swv[3];
        atomicAdd(out, tot * (1.0f / 131072.0f));
    }
}

extern "C" void kernel_launch(void* const* d_in, const int* in_sizes, int n_in,
                              void* d_out, int out_size, void* d_ws, size_t ws_size,
                              hipStream_t stream)
{
    const float* pred = (const float*)d_in[0];
    const float* gt   = (const float*)d_in[1];
    float* out        = (float*)d_out;

    // ws layout: [0,512K) wspred uints; [512K,+2K) wsgt; [1M,5M) Bfrag
    uint*   wspred = (uint*)d_ws;
    float*  wsgt   = (float*)((char*)d_ws + (512 << 10));
    short8* Bfrag  = (short8*)((char*)d_ws + (1 << 20));

    hipMemsetAsync(d_out, 0, sizeof(float), stream);

    chamfer_prep<<<dim3((32 * NBT * 64) / TPBP), dim3(TPBP), 0, stream>>>(
        pred, Bfrag, wspred);
    chamfer_mfma<<<dim3(GRID_MAIN), dim3(TPBM), 0, stream>>>(
        gt, wspred, wsgt, Bfrag);
    chamfer_finish<<<dim3(128), dim3(TPBP), 0, stream>>>(wspred, wsgt, out);
}